// Round 3
// baseline (416.517 us; speedup 1.0000x reference)
//
#include <hip/hip_runtime.h>
#include <hip/hip_bf16.h>
#include <math.h>

typedef unsigned short ushort_t;
typedef unsigned int u32;

constexpr int D  = 512;
constexpr int T  = 8192;
constexpr int B  = 8;
constexpr int H  = 8;
constexpr int KS = 64;
constexpr int HD = 64;
constexpr float SCALE = 0.125f;
constexpr float LNEPS = 1e-5f;
constexpr float EPS   = 1e-20f;

constexpr int TC  = 128;   // tokens per chunk
constexpr int CPB = 2;     // chunks per block

// ws layout (float units)
constexpr size_t OFF_S    = 0;         // 64*512
constexpr size_t OFF_BQ   = 32768;     // 512
constexpr size_t OFF_SACC = 33280;     // 8*8*64*64 = 262144
constexpr size_t OFF_CACC = 295424;    // 8*8*64 = 4096
constexpr size_t OFF_WB2  = 299520;    // bf16[1024*512] (1 MB)
constexpr size_t OFF_XB   = 561664;    // bf16[B*T*D] (64 MB)
constexpr size_t WS_NEED  = (OFF_XB + (size_t)B*T*D/2) * 4;  // bytes

typedef __attribute__((ext_vector_type(8))) short bf16x8;
typedef __attribute__((ext_vector_type(4))) float f32x4;
typedef __attribute__((ext_vector_type(4))) unsigned short us4;

typedef const __attribute__((address_space(1))) u32* gas_ptr;
typedef __attribute__((address_space(3))) u32* las_ptr;

__device__ __forceinline__ void gload16(const void* g, void* l) {
  __builtin_amdgcn_global_load_lds((gas_ptr)g, (las_ptr)l, 16, 0, 0);
}

__device__ __forceinline__ ushort_t f2bf(float x) {
  __hip_bfloat16 t = __float2bfloat16(x);
  return *(ushort_t*)&t;
}

__device__ __forceinline__ u32 pk2bf(float x, float y) {
  __hip_bfloat162 t = __float22bfloat162_rn(make_float2(x, y));
  return *(u32*)&t;
}

__device__ __forceinline__ bf16x8 cvt8(f32x4 a, f32x4 b) {
  union { bf16x8 v; u32 u[4]; } r;
  r.u[0] = pk2bf(a.x, a.y); r.u[1] = pk2bf(a.z, a.w);
  r.u[2] = pk2bf(b.x, b.y); r.u[3] = pk2bf(b.z, b.w);
  return r.v;
}

// ---------- setup: layernorm of slots ----------
__global__ void ln_slots_kernel(const float* __restrict__ slots_w,
                                const float* __restrict__ g, const float* __restrict__ b,
                                float* __restrict__ S) {
  __shared__ float red[8];
  int k = blockIdx.x;
  int tid = threadIdx.x;
  float x0 = slots_w[k*D + tid];
  float x1 = slots_w[k*D + tid + 256];
  float s1 = x0 + x1, s2 = x0*x0 + x1*x1;
  for (int off = 32; off; off >>= 1) { s1 += __shfl_xor(s1, off); s2 += __shfl_xor(s2, off); }
  if ((tid & 63) == 0) { red[tid >> 6] = s1; red[4 + (tid >> 6)] = s2; }
  __syncthreads();
  s1 = red[0] + red[1] + red[2] + red[3];
  s2 = red[4] + red[5] + red[6] + red[7];
  float mu = s1 / D;
  float var = s2 / D - mu * mu;
  float rs = rsqrtf(var + LNEPS);
  S[k*D + tid]       = (x0 - mu) * rs * g[tid]       + b[tid];
  S[k*D + tid + 256] = (x1 - mu) * rs * g[tid + 256] + b[tid + 256];
}

// ---------- setup: Wb2[(h*128+k)][in] = bf16(scale * sum_d S[k][h*64+d] * Wk[h*64+d][in]) ----------
__global__ void weff_kernel(const float* __restrict__ S, const float* __restrict__ Wk,
                            ushort_t* __restrict__ Wb2) {
  int gid = blockIdx.x * 256 + threadIdx.x;
  int in = gid & 511;
  int hk = gid >> 9;
  int h = hk >> 6, k = hk & 63;
  const float* srow = S + k*D + h*HD;
  const float* wcol = Wk + (size_t)(h*HD)*D + in;
  float acc = 0.f;
  #pragma unroll 8
  for (int d = 0; d < HD; ++d) acc += srow[d] * wcol[(size_t)d*D];
  Wb2[(size_t)(h*128 + k)*D + in] = f2bf(acc * SCALE);
}

__global__ void bq_kernel(const float* __restrict__ S, const float* __restrict__ bk,
                          float* __restrict__ bq) {
  int hk = blockIdx.x * 256 + threadIdx.x;
  int h = hk >> 6, k = hk & 63;
  float acc = 0.f;
  for (int d = 0; d < HD; ++d) acc += S[k*D + h*HD + d] * bk[h*HD + d];
  bq[hk] = acc * SCALE;
}

__global__ void wvcopy_kernel(const float* __restrict__ Wv, ushort_t* __restrict__ Wb2) {
  int gid = blockIdx.x * 256 + threadIdx.x;
  int in = gid & 511;
  int hd = gid >> 9;
  int h = hd >> 6, d = hd & 63;
  Wb2[(size_t)(h*128 + 64 + d)*D + in] = f2bf(Wv[(size_t)hd*D + in]);
}

__global__ void zero_kernel(float* __restrict__ p, int n) {
  int gid = blockIdx.x * 256 + threadIdx.x;
  if (gid < n) p[gid] = 0.f;
}

// ---------- X -> bf16 ----------
__global__ void xcvt_kernel(const float* __restrict__ X, ushort_t* __restrict__ Xb) {
  size_t i = ((size_t)blockIdx.x * 256 + threadIdx.x) * 8;
  f32x4 a = *(const f32x4*)(X + i);
  f32x4 b = *(const f32x4*)(X + i + 4);
  *(bf16x8*)(Xb + i) = cvt8(a, b);
}

// ---------- main fused MFMA kernel (bf16 X path) ----------
// LDS chunk swizzle: 16B chunk (row, kc) stored at slot row*4 + (kc ^ ((row>>1)&3)).
// Fragment read (lane m16,q) needs global chunk kc=q -> slot row*4 + (q ^ ((m16>>1)&3)):
// bank group = 4*(m16&1) + (q^((m16>>1)&3)) takes all 8 values over m16 -> 2-way (free).
__global__ __launch_bounds__(256, 4) void main_kernel_bf16(
    const ushort_t* __restrict__ Xb, const ushort_t* __restrict__ Wb2,
    const float* __restrict__ bq, const float* __restrict__ bv,
    float* __restrict__ Sacc, float* __restrict__ Cacc) {
  __shared__ __align__(16) char smem[34816];
  ushort_t* A_lds = (ushort_t*)smem;                  // 512 x 16B = 8 KB
  ushort_t* B_lds = (ushort_t*)(smem + 8192);         // 8 KB
  ushort_t* W_lds = (ushort_t*)smem;                  // [64 slots][136 tokens]
  ushort_t* V_lds = (ushort_t*)(smem + 17408);        // [64 dims ][136 tokens]

  const int tid  = threadIdx.x;
  const int lane = tid & 63, w = tid >> 6;
  const int wm = w & 1, wn = w >> 1;
  const int m16 = lane & 15, q = lane >> 4;
  const int kq = q ^ ((m16 >> 1) & 3);                // swizzled chunk idx for frag reads

  const int id = blockIdx.x;
  const int h  = (id >> 3) & 7;
  const int cg = (id & 7) | ((id >> 6) << 3);         // 0..255
  const int bh = (cg >> 5) * H + h;

  f32x4 acc2[4] = {};
  float csum[4] = {0.f, 0.f, 0.f, 0.f};

  for (int cc = 0; cc < CPB; ++cc) {
    const ushort_t* Xc = Xb + (size_t)(cg * CPB + cc) * TC * D;
    f32x4 acc[4][4] = {};

    for (int kb = 0; kb < D; kb += 32) {
      __syncthreads();
      #pragma unroll
      for (int m = 0; m < 2; ++m) {
        int li = tid + m * 256;                       // 0..511
        int row = li >> 2;
        int kc = (li & 3) ^ ((row >> 1) & 3);
        gload16(Xc + (size_t)row * D + kb + kc * 8, A_lds + (size_t)li * 8);
      }
      #pragma unroll
      for (int m = 0; m < 2; ++m) {
        int li = tid + m * 256;
        int col = li >> 2;
        int kc = (li & 3) ^ ((col >> 1) & 3);
        gload16(Wb2 + (size_t)(h * 128 + col) * D + kb + kc * 8, B_lds + (size_t)li * 8);
      }
      __syncthreads();
      bf16x8 af[4], bfv[4];
      #pragma unroll
      for (int i = 0; i < 4; ++i)
        af[i] = *(const bf16x8*)(A_lds + (size_t)(((wm*64 + i*16 + m16) << 2) | kq) * 8);
      #pragma unroll
      for (int j = 0; j < 4; ++j)
        bfv[j] = *(const bf16x8*)(B_lds + (size_t)(((wn*64 + j*16 + m16) << 2) | kq) * 8);
      #pragma unroll
      for (int i = 0; i < 4; ++i)
        #pragma unroll
        for (int j = 0; j < 4; ++j)
          acc[i][j] = __builtin_amdgcn_mfma_f32_16x16x32_bf16(af[i], bfv[j], acc[i][j], 0, 0, 0);
    }
    __syncthreads();

    if (wn == 0) {
      float bqv[4];
      #pragma unroll
      for (int j = 0; j < 4; ++j) bqv[j] = bq[h * KS + j * 16 + m16];
      #pragma unroll
      for (int i = 0; i < 4; ++i) {
        us4 wp[4];
        #pragma unroll
        for (int r = 0; r < 4; ++r) {
          float v0 = acc[i][0][r] + bqv[0];
          float v1 = acc[i][1][r] + bqv[1];
          float v2 = acc[i][2][r] + bqv[2];
          float v3 = acc[i][3][r] + bqv[3];
          float mx = fmaxf(fmaxf(v0, v1), fmaxf(v2, v3));
          mx = fmaxf(mx, __shfl_xor(mx, 1));
          mx = fmaxf(mx, __shfl_xor(mx, 2));
          mx = fmaxf(mx, __shfl_xor(mx, 4));
          mx = fmaxf(mx, __shfl_xor(mx, 8));
          v0 = __expf(v0 - mx); v1 = __expf(v1 - mx);
          v2 = __expf(v2 - mx); v3 = __expf(v3 - mx);
          float s = v0 + v1 + v2 + v3;
          s += __shfl_xor(s, 1); s += __shfl_xor(s, 2);
          s += __shfl_xor(s, 4); s += __shfl_xor(s, 8);
          float inv = __builtin_amdgcn_rcpf(s);
          v0 *= inv; v1 *= inv; v2 *= inv; v3 *= inv;
          csum[0] += v0; csum[1] += v1; csum[2] += v2; csum[3] += v3;
          wp[0][r] = f2bf(v0); wp[1][r] = f2bf(v1);
          wp[2][r] = f2bf(v2); wp[3][r] = f2bf(v3);
        }
        #pragma unroll
        for (int j = 0; j < 4; ++j)
          *(us4*)(W_lds + (j * 16 + m16) * 136 + wm * 64 + i * 16 + q * 4) = wp[j];
      }
    } else {
      float bvv[4];
      #pragma unroll
      for (int j = 0; j < 4; ++j) bvv[j] = bv[h * HD + j * 16 + m16];
      #pragma unroll
      for (int i = 0; i < 4; ++i) {
        #pragma unroll
        for (int j = 0; j < 4; ++j) {
          us4 pk;
          pk.x = f2bf(acc[i][j][0] + bvv[j]);
          pk.y = f2bf(acc[i][j][1] + bvv[j]);
          pk.z = f2bf(acc[i][j][2] + bvv[j]);
          pk.w = f2bf(acc[i][j][3] + bvv[j]);
          *(us4*)(V_lds + (j * 16 + m16) * 136 + wm * 64 + i * 16 + q * 4) = pk;
        }
      }
    }
    __syncthreads();

    #pragma unroll
    for (int kk = 0; kk < 4; ++kk) {
      bf16x8 a = *(const bf16x8*)(W_lds + (w * 16 + m16) * 136 + kk * 32 + q * 8);
      #pragma unroll
      for (int j = 0; j < 4; ++j) {
        bf16x8 bb = *(const bf16x8*)(V_lds + (j * 16 + m16) * 136 + kk * 32 + q * 8);
        acc2[j] = __builtin_amdgcn_mfma_f32_16x16x32_bf16(a, bb, acc2[j], 0, 0, 0);
      }
    }
  }

  float* Sb = Sacc + (size_t)bh * KS * HD;
  #pragma unroll
  for (int j = 0; j < 4; ++j)
    #pragma unroll
    for (int r = 0; r < 4; ++r)
      atomicAdd(Sb + (w * 16 + q * 4 + r) * HD + j * 16 + m16, acc2[j][r]);

  if (wn == 0) {
    #pragma unroll
    for (int j = 0; j < 4; ++j) {
      float c = csum[j];
      c += __shfl_xor(c, 16);
      c += __shfl_xor(c, 32);
      if (q == 0) atomicAdd(Cacc + (size_t)bh * KS + j * 16 + m16, c);
    }
  }
}

// ---------- fallback main kernel (fp32 X, round-2 version) for small ws ----------
__global__ __launch_bounds__(256, 3) void main_kernel_f32(
    const float* __restrict__ X, const ushort_t* __restrict__ Wb2,
    const float* __restrict__ bq, const float* __restrict__ bv,
    float* __restrict__ Sacc, float* __restrict__ Cacc) {
  __shared__ __align__(16) char smem[34816];
  float*    A_lds = (float*)smem;
  ushort_t* B_lds = (ushort_t*)(smem + 16384);
  ushort_t* W_lds = (ushort_t*)smem;
  ushort_t* V_lds = (ushort_t*)(smem + 17408);

  const int tid  = threadIdx.x;
  const int lane = tid & 63, w = tid >> 6;
  const int wm = w & 1, wn = w >> 1;
  const int m16 = lane & 15, q = lane >> 4;

  const int id = blockIdx.x;
  const int h  = (id >> 3) & 7;
  const int cg = (id & 7) | ((id >> 6) << 3);
  const int bh = (cg >> 5) * H + h;

  f32x4 acc2[4] = {};
  float csum[4] = {0.f, 0.f, 0.f, 0.f};

  for (int cc = 0; cc < CPB; ++cc) {
    const float* Xc = X + (size_t)(cg * CPB + cc) * TC * D;
    f32x4 acc[4][4] = {};
    for (int kb = 0; kb < D; kb += 32) {
      __syncthreads();
      #pragma unroll
      for (int m = 0; m < 4; ++m) {
        int li = tid + m * 256;
        int row = li >> 3, c = li & 7;
        gload16(Xc + (size_t)row * D + kb + c * 4, A_lds + (size_t)li * 4);
      }
      #pragma unroll
      for (int m = 0; m < 2; ++m) {
        int li = tid + m * 256;
        int col = li >> 2, c = li & 3;
        gload16(Wb2 + (size_t)(h * 128 + col) * D + kb + c * 8, B_lds + (size_t)li * 8);
      }
      __syncthreads();
      bf16x8 af[4], bfv[4];
      #pragma unroll
      for (int i = 0; i < 4; ++i) {
        const f32x4* ap = (const f32x4*)(A_lds + (wm * 64 + i * 16 + m16) * 32 + q * 8);
        af[i] = cvt8(ap[0], ap[1]);
      }
      #pragma unroll
      for (int j = 0; j < 4; ++j)
        bfv[j] = *(const bf16x8*)(B_lds + (wn * 64 + j * 16 + m16) * 32 + q * 8);
      #pragma unroll
      for (int i = 0; i < 4; ++i)
        #pragma unroll
        for (int j = 0; j < 4; ++j)
          acc[i][j] = __builtin_amdgcn_mfma_f32_16x16x32_bf16(af[i], bfv[j], acc[i][j], 0, 0, 0);
    }
    __syncthreads();

    if (wn == 0) {
      float bqv[4];
      #pragma unroll
      for (int j = 0; j < 4; ++j) bqv[j] = bq[h * KS + j * 16 + m16];
      #pragma unroll
      for (int i = 0; i < 4; ++i) {
        us4 wp[4];
        #pragma unroll
        for (int r = 0; r < 4; ++r) {
          float v0 = acc[i][0][r] + bqv[0];
          float v1 = acc[i][1][r] + bqv[1];
          float v2 = acc[i][2][r] + bqv[2];
          float v3 = acc[i][3][r] + bqv[3];
          float mx = fmaxf(fmaxf(v0, v1), fmaxf(v2, v3));
          mx = fmaxf(mx, __shfl_xor(mx, 1));
          mx = fmaxf(mx, __shfl_xor(mx, 2));
          mx = fmaxf(mx, __shfl_xor(mx, 4));
          mx = fmaxf(mx, __shfl_xor(mx, 8));
          v0 = __expf(v0 - mx); v1 = __expf(v1 - mx);
          v2 = __expf(v2 - mx); v3 = __expf(v3 - mx);
          float s = v0 + v1 + v2 + v3;
          s += __shfl_xor(s, 1); s += __shfl_xor(s, 2);
          s += __shfl_xor(s, 4); s += __shfl_xor(s, 8);
          float inv = __builtin_amdgcn_rcpf(s);
          v0 *= inv; v1 *= inv; v2 *= inv; v3 *= inv;
          csum[0] += v0; csum[1] += v1; csum[2] += v2; csum[3] += v3;
          wp[0][r] = f2bf(v0); wp[1][r] = f2bf(v1);
          wp[2][r] = f2bf(v2); wp[3][r] = f2bf(v3);
        }
        #pragma unroll
        for (int j = 0; j < 4; ++j)
          *(us4*)(W_lds + (j * 16 + m16) * 136 + wm * 64 + i * 16 + q * 4) = wp[j];
      }
    } else {
      float bvv[4];
      #pragma unroll
      for (int j = 0; j < 4; ++j) bvv[j] = bv[h * HD + j * 16 + m16];
      #pragma unroll
      for (int i = 0; i < 4; ++i) {
        #pragma unroll
        for (int j = 0; j < 4; ++j) {
          us4 pk;
          pk.x = f2bf(acc[i][j][0] + bvv[j]);
          pk.y = f2bf(acc[i][j][1] + bvv[j]);
          pk.z = f2bf(acc[i][j][2] + bvv[j]);
          pk.w = f2bf(acc[i][j][3] + bvv[j]);
          *(us4*)(V_lds + (j * 16 + m16) * 136 + wm * 64 + i * 16 + q * 4) = pk;
        }
      }
    }
    __syncthreads();

    #pragma unroll
    for (int kk = 0; kk < 4; ++kk) {
      bf16x8 a = *(const bf16x8*)(W_lds + (w * 16 + m16) * 136 + kk * 32 + q * 8);
      #pragma unroll
      for (int j = 0; j < 4; ++j) {
        bf16x8 bb = *(const bf16x8*)(V_lds + (j * 16 + m16) * 136 + kk * 32 + q * 8);
        acc2[j] = __builtin_amdgcn_mfma_f32_16x16x32_bf16(a, bb, acc2[j], 0, 0, 0);
      }
    }
  }

  float* Sb = Sacc + (size_t)bh * KS * HD;
  #pragma unroll
  for (int j = 0; j < 4; ++j)
    #pragma unroll
    for (int r = 0; r < 4; ++r)
      atomicAdd(Sb + (w * 16 + q * 4 + r) * HD + j * 16 + m16, acc2[j][r]);

  if (wn == 0) {
    #pragma unroll
    for (int j = 0; j < 4; ++j) {
      float c = csum[j];
      c += __shfl_xor(c, 16);
      c += __shfl_xor(c, 32);
      if (q == 0) atomicAdd(Cacc + (size_t)bh * KS + j * 16 + m16, c);
    }
  }
}

// ---------- finalize ----------
__global__ void finalize_kernel(const float* __restrict__ Sacc, const float* __restrict__ Cacc,
                                const float* __restrict__ g, const float* __restrict__ bb,
                                float* __restrict__ out) {
  __shared__ float red[8];
  int bk_ = blockIdx.x;
  int b = bk_ >> 6, k = bk_ & 63;
  int tid = threadIdx.x;
  float v[2];
  #pragma unroll
  for (int m = 0; m < 2; ++m) {
    int d = tid + m*256;
    int h = d >> 6, dd = d & 63;
    float c = Cacc[((size_t)b*H + h)*KS + k];
    v[m] = Sacc[(((size_t)b*H + h)*KS + k)*HD + dd] / (c + EPS);
  }
  float s1 = v[0] + v[1], s2 = v[0]*v[0] + v[1]*v[1];
  for (int off = 32; off; off >>= 1) { s1 += __shfl_xor(s1, off); s2 += __shfl_xor(s2, off); }
  if ((tid & 63) == 0) { red[tid >> 6] = s1; red[4 + (tid >> 6)] = s2; }
  __syncthreads();
  s1 = red[0] + red[1] + red[2] + red[3];
  s2 = red[4] + red[5] + red[6] + red[7];
  float mu = s1 / D;
  float var = s2 / D - mu * mu;
  float rs = rsqrtf(var + LNEPS);
  #pragma unroll
  for (int m = 0; m < 2; ++m) {
    int d = tid + m*256;
    out[(size_t)bk_*D + d] = (v[m] - mu) * rs * g[d] + bb[d];
  }
}

extern "C" void kernel_launch(void* const* d_in, const int* in_sizes, int n_in,
                              void* d_out, int out_size, void* d_ws, size_t ws_size,
                              hipStream_t stream) {
  const float* X       = (const float*)d_in[0];
  const float* slots_w = (const float*)d_in[1];
  const float* g_slots = (const float*)d_in[2];
  const float* b_slots = (const float*)d_in[3];
  const float* Wk      = (const float*)d_in[4];
  const float* bk      = (const float*)d_in[5];
  const float* Wv      = (const float*)d_in[6];
  const float* bv      = (const float*)d_in[7];
  const float* g_after = (const float*)d_in[8];
  const float* b_after = (const float*)d_in[9];
  float* ws   = (float*)d_ws;
  float* S    = ws + OFF_S;
  float* bq   = ws + OFF_BQ;
  float* Sacc = ws + OFF_SACC;
  float* Cacc = ws + OFF_CACC;
  ushort_t* Wb2 = (ushort_t*)(ws + OFF_WB2);
  ushort_t* Xb  = (ushort_t*)(ws + OFF_XB);
  float* out  = (float*)d_out;

  hipLaunchKernelGGL(ln_slots_kernel, dim3(64), dim3(256), 0, stream, slots_w, g_slots, b_slots, S);
  hipLaunchKernelGGL(weff_kernel, dim3(1024), dim3(256), 0, stream, S, Wk, Wb2);
  hipLaunchKernelGGL(bq_kernel, dim3(2), dim3(256), 0, stream, S, bk, bq);
  hipLaunchKernelGGL(wvcopy_kernel, dim3(1024), dim3(256), 0, stream, Wv, Wb2);
  hipLaunchKernelGGL(zero_kernel, dim3(1040), dim3(256), 0, stream, Sacc, 266240);
  if (ws_size >= WS_NEED) {
    hipLaunchKernelGGL(xcvt_kernel, dim3(16384), dim3(256), 0, stream, X, Xb);
    hipLaunchKernelGGL(main_kernel_bf16, dim3(2048), dim3(256), 0, stream,
                       Xb, Wb2, bq, bv, Sacc, Cacc);
  } else {
    hipLaunchKernelGGL(main_kernel_f32, dim3(2048), dim3(256), 0, stream,
                       X, Wb2, bq, bv, Sacc, Cacc);
  }
  hipLaunchKernelGGL(finalize_kernel, dim3(B * KS), dim3(256), 0, stream,
                     Sacc, Cacc, g_after, b_after, out);
}

// Round 4
// 416.499 us; speedup vs baseline: 1.0000x; 1.0000x over previous
//
#include <hip/hip_runtime.h>
#include <hip/hip_bf16.h>
#include <math.h>

typedef unsigned short ushort_t;
typedef unsigned int u32;

constexpr int D  = 512;
constexpr int T  = 8192;
constexpr int B  = 8;
constexpr int H  = 8;
constexpr int KS = 64;
constexpr int HD = 64;
constexpr float SCALE = 0.125f;
constexpr float LNEPS = 1e-5f;
constexpr float EPS   = 1e-20f;

constexpr int TC = 128;   // tokens per block (main kernel)

// ws layout (float units) — no X copy this round (r3 lesson: bouncing X through ws hurt)
constexpr size_t OFF_S    = 0;         // 64*512
constexpr size_t OFF_BQ   = 32768;     // 512
constexpr size_t OFF_SACC = 33280;     // 8*8*64*64 = 262144
constexpr size_t OFF_CACC = 295424;    // 8*8*64 = 4096
constexpr size_t OFF_WB2  = 299520;    // bf16[1024*512] (1 MB)

constexpr int MAIN_LDS = 147456;       // 128 KB X-tile + 8 KB W + 8 KB V

typedef __attribute__((ext_vector_type(8))) short bf16x8;
typedef __attribute__((ext_vector_type(4))) float f32x4;
typedef __attribute__((ext_vector_type(4))) unsigned short us4;

typedef const __attribute__((address_space(1))) u32* gas_ptr;
typedef __attribute__((address_space(3))) u32* las_ptr;

__device__ __forceinline__ void gload16(const void* g, void* l) {
  __builtin_amdgcn_global_load_lds((gas_ptr)g, (las_ptr)l, 16, 0, 0);
}

__device__ __forceinline__ ushort_t f2bf(float x) {
  __hip_bfloat16 t = __float2bfloat16(x);
  return *(ushort_t*)&t;
}

__device__ __forceinline__ u32 pk2bf(float x, float y) {
  __hip_bfloat162 t = __float22bfloat162_rn(make_float2(x, y));
  return *(u32*)&t;
}

__device__ __forceinline__ bf16x8 cvt8(f32x4 a, f32x4 b) {
  union { bf16x8 v; u32 u[4]; } r;
  r.u[0] = pk2bf(a.x, a.y); r.u[1] = pk2bf(a.z, a.w);
  r.u[2] = pk2bf(b.x, b.y); r.u[3] = pk2bf(b.z, b.w);
  return r.v;
}

// ---------- setup: layernorm of slots ----------
__global__ void ln_slots_kernel(const float* __restrict__ slots_w,
                                const float* __restrict__ g, const float* __restrict__ b,
                                float* __restrict__ S) {
  __shared__ float red[8];
  int k = blockIdx.x;
  int tid = threadIdx.x;
  float x0 = slots_w[k*D + tid];
  float x1 = slots_w[k*D + tid + 256];
  float s1 = x0 + x1, s2 = x0*x0 + x1*x1;
  for (int off = 32; off; off >>= 1) { s1 += __shfl_xor(s1, off); s2 += __shfl_xor(s2, off); }
  if ((tid & 63) == 0) { red[tid >> 6] = s1; red[4 + (tid >> 6)] = s2; }
  __syncthreads();
  s1 = red[0] + red[1] + red[2] + red[3];
  s2 = red[4] + red[5] + red[6] + red[7];
  float mu = s1 / D;
  float var = s2 / D - mu * mu;
  float rs = rsqrtf(var + LNEPS);
  S[k*D + tid]       = (x0 - mu) * rs * g[tid]       + b[tid];
  S[k*D + tid + 256] = (x1 - mu) * rs * g[tid + 256] + b[tid + 256];
}

// ---------- setup: Wb2[(h*128+k)][in] = bf16(scale * sum_d S[k][h*64+d] * Wk[h*64+d][in]) ----------
__global__ void weff_kernel(const float* __restrict__ S, const float* __restrict__ Wk,
                            ushort_t* __restrict__ Wb2) {
  int gid = blockIdx.x * 256 + threadIdx.x;
  int in = gid & 511;
  int hk = gid >> 9;
  int h = hk >> 6, k = hk & 63;
  const float* srow = S + k*D + h*HD;
  const float* wcol = Wk + (size_t)(h*HD)*D + in;
  float acc = 0.f;
  #pragma unroll 8
  for (int d = 0; d < HD; ++d) acc += srow[d] * wcol[(size_t)d*D];
  Wb2[(size_t)(h*128 + k)*D + in] = f2bf(acc * SCALE);
}

__global__ void bq_kernel(const float* __restrict__ S, const float* __restrict__ bk,
                          float* __restrict__ bq) {
  int hk = blockIdx.x * 256 + threadIdx.x;
  int h = hk >> 6, k = hk & 63;
  float acc = 0.f;
  for (int d = 0; d < HD; ++d) acc += S[k*D + h*HD + d] * bk[h*HD + d];
  bq[hk] = acc * SCALE;
}

__global__ void wvcopy_kernel(const float* __restrict__ Wv, ushort_t* __restrict__ Wb2) {
  int gid = blockIdx.x * 256 + threadIdx.x;
  int in = gid & 511;
  int hd = gid >> 9;
  int h = hd >> 6, d = hd & 63;
  Wb2[(size_t)(h*128 + 64 + d)*D + in] = f2bf(Wv[(size_t)hd*D + in]);
}

__global__ void zero_kernel(float* __restrict__ p, int n) {
  int gid = blockIdx.x * 256 + threadIdx.x;
  if (gid < n) p[gid] = 0.f;
}

// ---------- main kernel: one block = 128 tokens, ALL heads; X staged once ----------
// 512 threads = 8 waves. Wave w: th = w&1 (token half: 64 tokens), cqq = w>>1:
//   cqq 0 = pair-head-A logits, 1 = A values, 2 = B logits, 3 = B values.
// K-loop is barrier-free: A frags from read-only LDS X-tile, B frags straight
// from L2-resident Wb2 (16 lanes x 64B lines per read). Heads in 4 pairs.
// LDS X-tile swizzle: chunk (token,c) at token*64 + (c ^ (token&7)) -> 2-way reads (free).
__global__ __launch_bounds__(512, 2) void main_kernel_ah(
    const float* __restrict__ X, const ushort_t* __restrict__ Wb2,
    const float* __restrict__ bq, const float* __restrict__ bv,
    float* __restrict__ Sacc, float* __restrict__ Cacc) {
  extern __shared__ __align__(16) char smem[];
  ushort_t* X_lds = (ushort_t*)smem;               // 128 tokens x 64 chunks x 16B = 128 KB
  ushort_t* W_lds = (ushort_t*)(smem + 131072);    // 64 slots x 8 tchunks x 16B = 8 KB (one half)
  ushort_t* V_lds = (ushort_t*)(smem + 139264);    // 64 dims  x 8 tchunks x 16B = 8 KB

  const int tid = threadIdx.x;
  const int w = tid >> 6, lane = tid & 63;
  const int m16 = lane & 15, q = lane >> 4;
  const int th = w & 1, cqq = w >> 1;
  const int bid = blockIdx.x;
  const int bb = bid >> 6;                          // batch
  const float* Xc = X + (size_t)bid * TC * D;

  // ---- stage X chunk -> LDS bf16 (read once from HBM, perfectly coalesced) ----
  #pragma unroll
  for (int m = 0; m < 16; ++m) {
    int C = m * 512 + tid;                          // 16B-chunk id, 0..8191
    int token = C >> 6, c = C & 63;
    const f32x4* src = (const f32x4*)(Xc + (size_t)C * 8);
    f32x4 a = src[0], b2 = src[1];
    *(bf16x8*)(X_lds + ((size_t)token * 64 + (c ^ (token & 7))) * 8) = cvt8(a, b2);
  }
  __syncthreads();

  const int hh_my = cqq >> 1;                       // which head of the pair this wave computes
  const int isV   = cqq & 1;

  for (int p = 0; p < 4; ++p) {
    // ---- phase 1: 128 tokens x 256 cols (pair), K=512, barrier-free ----
    f32x4 acc[4][4] = {};
    const ushort_t* Bp = Wb2 + ((size_t)((p * 2 + hh_my) * 128 + isV * 64 + m16)) * D + q * 8;
    bf16x8 bnx[4];
    #pragma unroll
    for (int j = 0; j < 4; ++j) bnx[j] = *(const bf16x8*)(Bp + (size_t)j * 16 * D);
    #pragma unroll 2
    for (int it = 0; it < 16; ++it) {
      bf16x8 bc[4];
      #pragma unroll
      for (int j = 0; j < 4; ++j) bc[j] = bnx[j];
      if (it < 15) {
        #pragma unroll
        for (int j = 0; j < 4; ++j)
          bnx[j] = *(const bf16x8*)(Bp + (it + 1) * 32 + (size_t)j * 16 * D);
      }
      bf16x8 af[4];
      #pragma unroll
      for (int i = 0; i < 4; ++i) {
        int token = th * 64 + i * 16 + m16;
        af[i] = *(const bf16x8*)(X_lds + ((size_t)token * 64 + ((it * 4 + q) ^ (token & 7))) * 8);
      }
      #pragma unroll
      for (int i = 0; i < 4; ++i)
        #pragma unroll
        for (int j = 0; j < 4; ++j)
          acc[i][j] = __builtin_amdgcn_mfma_f32_16x16x32_bf16(af[i], bc[j], acc[i][j], 0, 0, 0);
    }

    // ---- per head: softmax -> LDS (A/B layout) -> phase-2 MFMA, token-halves ----
    for (int hh = 0; hh < 2; ++hh) {
      const int head = p * 2 + hh;
      const int bh = bb * 8 + head;
      const bool mine = (hh_my == hh);
      us4 pk[4][4];
      if (mine) {
        if (!isV) {
          float bqv[4];
          #pragma unroll
          for (int j = 0; j < 4; ++j) bqv[j] = bq[head * 64 + j * 16 + m16];
          float cs0 = 0.f, cs1 = 0.f, cs2 = 0.f, cs3 = 0.f;
          #pragma unroll
          for (int i = 0; i < 4; ++i) {
            #pragma unroll
            for (int r = 0; r < 4; ++r) {
              float v0 = acc[i][0][r] + bqv[0];
              float v1 = acc[i][1][r] + bqv[1];
              float v2 = acc[i][2][r] + bqv[2];
              float v3 = acc[i][3][r] + bqv[3];
              float mx = fmaxf(fmaxf(v0, v1), fmaxf(v2, v3));
              mx = fmaxf(mx, __shfl_xor(mx, 1));
              mx = fmaxf(mx, __shfl_xor(mx, 2));
              mx = fmaxf(mx, __shfl_xor(mx, 4));
              mx = fmaxf(mx, __shfl_xor(mx, 8));
              v0 = __expf(v0 - mx); v1 = __expf(v1 - mx);
              v2 = __expf(v2 - mx); v3 = __expf(v3 - mx);
              float s = v0 + v1 + v2 + v3;
              s += __shfl_xor(s, 1); s += __shfl_xor(s, 2);
              s += __shfl_xor(s, 4); s += __shfl_xor(s, 8);
              float inv = __builtin_amdgcn_rcpf(s);
              v0 *= inv; v1 *= inv; v2 *= inv; v3 *= inv;
              cs0 += v0; cs1 += v1; cs2 += v2; cs3 += v3;
              pk[i][0][r] = f2bf(v0); pk[i][1][r] = f2bf(v1);
              pk[i][2][r] = f2bf(v2); pk[i][3][r] = f2bf(v3);
            }
          }
          cs0 += __shfl_xor(cs0, 16); cs0 += __shfl_xor(cs0, 32);
          cs1 += __shfl_xor(cs1, 16); cs1 += __shfl_xor(cs1, 32);
          cs2 += __shfl_xor(cs2, 16); cs2 += __shfl_xor(cs2, 32);
          cs3 += __shfl_xor(cs3, 16); cs3 += __shfl_xor(cs3, 32);
          if (q == 0) {
            atomicAdd(Cacc + (size_t)bh * KS +  0 + m16, cs0);
            atomicAdd(Cacc + (size_t)bh * KS + 16 + m16, cs1);
            atomicAdd(Cacc + (size_t)bh * KS + 32 + m16, cs2);
            atomicAdd(Cacc + (size_t)bh * KS + 48 + m16, cs3);
          }
        } else {
          float bvv[4];
          #pragma unroll
          for (int j = 0; j < 4; ++j) bvv[j] = bv[head * 64 + j * 16 + m16];
          #pragma unroll
          for (int i = 0; i < 4; ++i)
            #pragma unroll
            for (int j = 0; j < 4; ++j) {
              pk[i][j][0] = f2bf(acc[i][j][0] + bvv[j]);
              pk[i][j][1] = f2bf(acc[i][j][1] + bvv[j]);
              pk[i][j][2] = f2bf(acc[i][j][2] + bvv[j]);
              pk[i][j][3] = f2bf(acc[i][j][3] + bvv[j]);
            }
        }
      }

      f32x4 acc2[2] = {};
      #pragma unroll
      for (int half = 0; half < 2; ++half) {
        __syncthreads();    // prev phase-2 reads of W/V region complete
        if (mine && th == half) {
          ushort_t* dst = isV ? V_lds : W_lds;
          #pragma unroll
          for (int i = 0; i < 4; ++i)
            #pragma unroll
            for (int j = 0; j < 4; ++j) {
              int rowv = j * 16 + m16;              // slot (W) or dim (V)
              int tc = i * 2 + (q >> 1);            // 8-token chunk within half
              *(us4*)(dst + ((size_t)rowv * 8 + (tc ^ (rowv & 7))) * 8 + (q & 1) * 4) = pk[i][j];
            }
        }
        __syncthreads();
        #pragma unroll
        for (int ks = 0; ks < 2; ++ks) {
          int tcc = ks * 4 + q;
          int sl = (w & 3) * 16 + m16;
          bf16x8 a2 = *(const bf16x8*)(W_lds + ((size_t)sl * 8 + (tcc ^ (m16 & 7))) * 8);
          #pragma unroll
          for (int jj = 0; jj < 2; ++jj) {
            int dm = (w >> 2) * 32 + jj * 16 + m16;
            bf16x8 b2v = *(const bf16x8*)(V_lds + ((size_t)dm * 8 + (tcc ^ (m16 & 7))) * 8);
            acc2[jj] = __builtin_amdgcn_mfma_f32_16x16x32_bf16(a2, b2v, acc2[jj], 0, 0, 0);
          }
        }
      }
      // flush this head's partial (disjoint (slot,dim) per wave within block)
      float* Sb = Sacc + (size_t)bh * KS * HD;
      #pragma unroll
      for (int jj = 0; jj < 2; ++jj)
        #pragma unroll
        for (int r = 0; r < 4; ++r)
          atomicAdd(Sb + ((w & 3) * 16 + q * 4 + r) * HD + (w >> 2) * 32 + jj * 16 + m16,
                    acc2[jj][r]);
    }
  }
}

// ---------- fallback main kernel (round-3 structure, static LDS) ----------
__global__ __launch_bounds__(256, 3) void main_kernel_f32(
    const float* __restrict__ X, const ushort_t* __restrict__ Wb2,
    const float* __restrict__ bq, const float* __restrict__ bv,
    float* __restrict__ Sacc, float* __restrict__ Cacc) {
  __shared__ __align__(16) char smem[34816];
  float*    A_lds = (float*)smem;
  ushort_t* B_lds = (ushort_t*)(smem + 16384);
  ushort_t* W_lds = (ushort_t*)smem;
  ushort_t* V_lds = (ushort_t*)(smem + 17408);

  const int tid  = threadIdx.x;
  const int lane = tid & 63, w = tid >> 6;
  const int wm = w & 1, wn = w >> 1;
  const int m16 = lane & 15, q = lane >> 4;

  const int id = blockIdx.x;
  const int h  = (id >> 3) & 7;
  const int cg = (id & 7) | ((id >> 6) << 3);
  const int bh = (cg >> 5) * H + h;

  f32x4 acc2[4] = {};
  float csum[4] = {0.f, 0.f, 0.f, 0.f};

  for (int cc = 0; cc < 2; ++cc) {
    const float* Xc = X + (size_t)(cg * 2 + cc) * 128 * D;
    f32x4 acc[4][4] = {};
    for (int kb = 0; kb < D; kb += 32) {
      __syncthreads();
      #pragma unroll
      for (int m = 0; m < 4; ++m) {
        int li = tid + m * 256;
        int row = li >> 3, c = li & 7;
        gload16(Xc + (size_t)row * D + kb + c * 4, A_lds + (size_t)li * 4);
      }
      #pragma unroll
      for (int m = 0; m < 2; ++m) {
        int li = tid + m * 256;
        int col = li >> 2, c = li & 3;
        gload16(Wb2 + (size_t)(h * 128 + col) * D + kb + c * 8, B_lds + (size_t)li * 8);
      }
      __syncthreads();
      bf16x8 af[4], bfv[4];
      #pragma unroll
      for (int i = 0; i < 4; ++i) {
        const f32x4* ap = (const f32x4*)(A_lds + (wm * 64 + i * 16 + m16) * 32 + q * 8);
        af[i] = cvt8(ap[0], ap[1]);
      }
      #pragma unroll
      for (int j = 0; j < 4; ++j)
        bfv[j] = *(const bf16x8*)(B_lds + (wn * 64 + j * 16 + m16) * 32 + q * 8);
      #pragma unroll
      for (int i = 0; i < 4; ++i)
        #pragma unroll
        for (int j = 0; j < 4; ++j)
          acc[i][j] = __builtin_amdgcn_mfma_f32_16x16x32_bf16(af[i], bfv[j], acc[i][j], 0, 0, 0);
    }
    __syncthreads();

    if (wn == 0) {
      float bqv[4];
      #pragma unroll
      for (int j = 0; j < 4; ++j) bqv[j] = bq[h * KS + j * 16 + m16];
      #pragma unroll
      for (int i = 0; i < 4; ++i) {
        us4 wp[4];
        #pragma unroll
        for (int r = 0; r < 4; ++r) {
          float v0 = acc[i][0][r] + bqv[0];
          float v1 = acc[i][1][r] + bqv[1];
          float v2 = acc[i][2][r] + bqv[2];
          float v3 = acc[i][3][r] + bqv[3];
          float mx = fmaxf(fmaxf(v0, v1), fmaxf(v2, v3));
          mx = fmaxf(mx, __shfl_xor(mx, 1));
          mx = fmaxf(mx, __shfl_xor(mx, 2));
          mx = fmaxf(mx, __shfl_xor(mx, 4));
          mx = fmaxf(mx, __shfl_xor(mx, 8));
          v0 = __expf(v0 - mx); v1 = __expf(v1 - mx);
          v2 = __expf(v2 - mx); v3 = __expf(v3 - mx);
          float s = v0 + v1 + v2 + v3;
          s += __shfl_xor(s, 1); s += __shfl_xor(s, 2);
          s += __shfl_xor(s, 4); s += __shfl_xor(s, 8);
          float inv = __builtin_amdgcn_rcpf(s);
          v0 *= inv; v1 *= inv; v2 *= inv; v3 *= inv;
          csum[0] += v0; csum[1] += v1; csum[2] += v2; csum[3] += v3;
          wp[0][r] = f2bf(v0); wp[1][r] = f2bf(v1);
          wp[2][r] = f2bf(v2); wp[3][r] = f2bf(v3);
        }
        #pragma unroll
        for (int j = 0; j < 4; ++j)
          *(us4*)(W_lds + (j * 16 + m16) * 136 + wm * 64 + i * 16 + q * 4) = wp[j];
      }
    } else {
      float bvv[4];
      #pragma unroll
      for (int j = 0; j < 4; ++j) bvv[j] = bv[h * HD + (j * 16 + m16 < 64 ? j * 16 + m16 : 0)];
      #pragma unroll
      for (int i = 0; i < 4; ++i)
        #pragma unroll
        for (int j = 0; j < 4; ++j) {
          us4 pkk;
          pkk[0] = f2bf(acc[i][j][0] + bvv[j]);
          pkk[1] = f2bf(acc[i][j][1] + bvv[j]);
          pkk[2] = f2bf(acc[i][j][2] + bvv[j]);
          pkk[3] = f2bf(acc[i][j][3] + bvv[j]);
          *(us4*)(V_lds + (j * 16 + m16) * 136 + wm * 64 + i * 16 + q * 4) = pkk;
        }
    }
    __syncthreads();

    #pragma unroll
    for (int kk = 0; kk < 4; ++kk) {
      bf16x8 a = *(const bf16x8*)(W_lds + (w * 16 + m16) * 136 + kk * 32 + q * 8);
      #pragma unroll
      for (int j = 0; j < 4; ++j) {
        bf16x8 bb = *(const bf16x8*)(V_lds + (j * 16 + m16) * 136 + kk * 32 + q * 8);
        acc2[j] = __builtin_amdgcn_mfma_f32_16x16x32_bf16(a, bb, acc2[j], 0, 0, 0);
      }
    }
  }

  float* Sb = Sacc + (size_t)bh * KS * HD;
  #pragma unroll
  for (int j = 0; j < 4; ++j)
    #pragma unroll
    for (int r = 0; r < 4; ++r)
      atomicAdd(Sb + (w * 16 + q * 4 + r) * HD + j * 16 + m16, acc2[j][r]);

  if (wn == 0) {
    #pragma unroll
    for (int j = 0; j < 4; ++j) {
      float c = csum[j];
      c += __shfl_xor(c, 16);
      c += __shfl_xor(c, 32);
      if (q == 0) atomicAdd(Cacc + (size_t)bh * KS + j * 16 + m16, c);
    }
  }
}

// ---------- finalize ----------
__global__ void finalize_kernel(const float* __restrict__ Sacc, const float* __restrict__ Cacc,
                                const float* __restrict__ g, const float* __restrict__ bb,
                                float* __restrict__ out) {
  __shared__ float red[8];
  int bk_ = blockIdx.x;
  int b = bk_ >> 6, k = bk_ & 63;
  int tid = threadIdx.x;
  float v[2];
  #pragma unroll
  for (int m = 0; m < 2; ++m) {
    int d = tid + m*256;
    int h = d >> 6, dd = d & 63;
    float c = Cacc[((size_t)b*H + h)*KS + k];
    v[m] = Sacc[(((size_t)b*H + h)*KS + k)*HD + dd] / (c + EPS);
  }
  float s1 = v[0] + v[1], s2 = v[0]*v[0] + v[1]*v[1];
  for (int off = 32; off; off >>= 1) { s1 += __shfl_xor(s1, off); s2 += __shfl_xor(s2, off); }
  if ((tid & 63) == 0) { red[tid >> 6] = s1; red[4 + (tid >> 6)] = s2; }
  __syncthreads();
  s1 = red[0] + red[1] + red[2] + red[3];
  s2 = red[4] + red[5] + red[6] + red[7];
  float mu = s1 / D;
  float var = s2 / D - mu * mu;
  float rs = rsqrtf(var + LNEPS);
  #pragma unroll
  for (int m = 0; m < 2; ++m) {
    int d = tid + m*256;
    out[(size_t)bk_*D + d] = (v[m] - mu) * rs * g[d] + bb[d];
  }
}

extern "C" void kernel_launch(void* const* d_in, const int* in_sizes, int n_in,
                              void* d_out, int out_size, void* d_ws, size_t ws_size,
                              hipStream_t stream) {
  const float* X       = (const float*)d_in[0];
  const float* slots_w = (const float*)d_in[1];
  const float* g_slots = (const float*)d_in[2];
  const float* b_slots = (const float*)d_in[3];
  const float* Wk      = (const float*)d_in[4];
  const float* bk      = (const float*)d_in[5];
  const float* Wv      = (const float*)d_in[6];
  const float* bv      = (const float*)d_in[7];
  const float* g_after = (const float*)d_in[8];
  const float* b_after = (const float*)d_in[9];
  float* ws   = (float*)d_ws;
  float* S    = ws + OFF_S;
  float* bq   = ws + OFF_BQ;
  float* Sacc = ws + OFF_SACC;
  float* Cacc = ws + OFF_CACC;
  ushort_t* Wb2 = (ushort_t*)(ws + OFF_WB2);
  float* out  = (float*)d_out;

  hipLaunchKernelGGL(ln_slots_kernel, dim3(64), dim3(256), 0, stream, slots_w, g_slots, b_slots, S);
  hipLaunchKernelGGL(weff_kernel, dim3(1024), dim3(256), 0, stream, S, Wk, Wb2);
  hipLaunchKernelGGL(bq_kernel, dim3(2), dim3(256), 0, stream, S, bk, bq);
  hipLaunchKernelGGL(wvcopy_kernel, dim3(1024), dim3(256), 0, stream, Wv, Wb2);
  hipLaunchKernelGGL(zero_kernel, dim3(1040), dim3(256), 0, stream, Sacc, 266240);

  hipError_t attr_ok = hipFuncSetAttribute(
      reinterpret_cast<const void*>(main_kernel_ah),
      hipFuncAttributeMaxDynamicSharedMemorySize, MAIN_LDS);
  if (attr_ok == hipSuccess) {
    hipLaunchKernelGGL(main_kernel_ah, dim3(B * T / TC), dim3(512), MAIN_LDS, stream,
                       X, Wb2, bq, bv, Sacc, Cacc);
  } else {
    hipLaunchKernelGGL(main_kernel_f32, dim3(2048), dim3(256), 0, stream,
                       X, Wb2, bq, bv, Sacc, Cacc);
  }
  hipLaunchKernelGGL(finalize_kernel, dim3(B * KS), dim3(256), 0, stream,
                     Sacc, Cacc, g_after, b_after, out);
}

// Round 6
// 379.375 us; speedup vs baseline: 1.0979x; 1.0979x over previous
//
#include <hip/hip_runtime.h>
#include <hip/hip_bf16.h>
#include <math.h>

typedef unsigned short ushort_t;
typedef unsigned int u32;

constexpr int D  = 512;
constexpr int T  = 8192;
constexpr int B  = 8;
constexpr int H  = 8;
constexpr int KS = 64;
constexpr int HD = 64;
constexpr float SCALE = 0.125f;
constexpr float LNEPS = 1e-5f;
constexpr float EPS   = 1e-20f;

// ws layout (float units). NOTE: Wb2 is 1024*512 bf16 = 262144 FLOATS (r5 bug:
// had 131072 -> Spart overlapped Wb2 -> garbage weights -> exp overflow -> NaN).
constexpr size_t OFF_BQ    = 0;          // 512 f
constexpr size_t OFF_WB2   = 512;        // bf16[1024*512] = 262144 f
constexpr size_t OFF_SPART = 262656;     // 2048 * 64*64 f = 8388608 f (32 MB)
constexpr size_t OFF_CPART = 8651264;    // 2048 * 128 f (two wave-halves per block)
// total = 8913408 f = 35.7 MB (ws known >= 69 MB from r3's bf16-path run)

typedef __attribute__((ext_vector_type(8))) short bf16x8;
typedef __attribute__((ext_vector_type(4))) float f32x4;
typedef __attribute__((ext_vector_type(4))) unsigned short us4;

typedef const __attribute__((address_space(1))) u32* gas_ptr;
typedef __attribute__((address_space(3))) u32* las_ptr;

__device__ __forceinline__ void gload16(const void* g, void* l) {
  __builtin_amdgcn_global_load_lds((gas_ptr)g, (las_ptr)l, 16, 0, 0);
}

__device__ __forceinline__ ushort_t f2bf(float x) {
  __hip_bfloat16 t = __float2bfloat16(x);
  return *(ushort_t*)&t;
}

__device__ __forceinline__ u32 pk2bf(float x, float y) {
  __hip_bfloat162 t = __float22bfloat162_rn(make_float2(x, y));
  return *(u32*)&t;
}

__device__ __forceinline__ bf16x8 cvt8(f32x4 a, f32x4 b) {
  union { bf16x8 v; u32 u[4]; } r;
  r.u[0] = pk2bf(a.x, a.y); r.u[1] = pk2bf(a.z, a.w);
  r.u[2] = pk2bf(b.x, b.y); r.u[3] = pk2bf(b.z, b.w);
  return r.v;
}

// ---------- fused setup: per-hk block does slot-LN (redundantly, cheap),
// Weff row, bq entry, and the Wv row copy. One dispatch replaces four. ----------
__global__ void setup_kernel(const float* __restrict__ slots_w,
                             const float* __restrict__ g, const float* __restrict__ b,
                             const float* __restrict__ Wk, const float* __restrict__ bk,
                             const float* __restrict__ Wv,
                             ushort_t* __restrict__ Wb2, float* __restrict__ bq) {
  __shared__ float S_lds[512];
  __shared__ float red[8];
  const int hk = blockIdx.x;            // 0..511
  const int h = hk >> 6, k = hk & 63;
  const int tid = threadIdx.x;

  float x0 = slots_w[k*D + tid];
  float x1 = slots_w[k*D + tid + 256];
  float s1 = x0 + x1, s2 = x0*x0 + x1*x1;
  for (int off = 32; off; off >>= 1) { s1 += __shfl_xor(s1, off); s2 += __shfl_xor(s2, off); }
  if ((tid & 63) == 0) { red[tid >> 6] = s1; red[4 + (tid >> 6)] = s2; }
  __syncthreads();
  s1 = red[0] + red[1] + red[2] + red[3];
  s2 = red[4] + red[5] + red[6] + red[7];
  float mu = s1 / D;
  float var = s2 / D - mu * mu;
  float rs = rsqrtf(var + LNEPS);
  S_lds[tid]       = (x0 - mu) * rs * g[tid]       + b[tid];
  S_lds[tid + 256] = (x1 - mu) * rs * g[tid + 256] + b[tid + 256];
  __syncthreads();

  // Weff row hk (512 outputs) + Wv row copy
  #pragma unroll
  for (int rep = 0; rep < 2; ++rep) {
    int in = tid + rep * 256;
    float acc = 0.f;
    #pragma unroll 8
    for (int d = 0; d < 64; ++d)
      acc += S_lds[h*64 + d] * Wk[(size_t)(h*64 + d)*D + in];
    Wb2[(size_t)(h*128 + k)*D + in] = f2bf(acc * SCALE);
    Wb2[(size_t)(h*128 + 64 + k)*D + in] = f2bf(Wv[(size_t)hk*D + in]);
  }
  // bq[hk]
  if (tid < 64) {
    float p = S_lds[h*64 + tid] * bk[h*64 + tid];
    for (int off = 32; off; off >>= 1) p += __shfl_xor(p, off);
    if (tid == 0) bq[hk] = p * SCALE;
  }
}

// ---------- main kernel: BK=64, bf16 A via register cvt, conflict-free swizzle,
// clamped no-max softmax, per-wave partial stores (no atomics) ----------
// grid 2048 = (cg 256 x head 8), 256 threads (4 waves, 2x2).
// LDS chunk swizzle (A and B): 16B chunk c of row r stored at slot c^(r&7);
// frag read lane (m16,q), k-sub ks reads slot (ks*4+q)^(m16&7) -> conflict-free.
__global__ __launch_bounds__(256, 4) void main_kernel5(
    const float* __restrict__ X, const ushort_t* __restrict__ Wb2,
    const float* __restrict__ bq, const float* __restrict__ bv,
    float* __restrict__ Spart, float* __restrict__ Cpart) {
  __shared__ __align__(16) char smem[34816];
  ushort_t* A_lds = (ushort_t*)smem;            // 128 tok x 8 chunks x 16B = 16 KB
  ushort_t* B_lds = (ushort_t*)(smem + 16384);  // 128 col x 8 chunks = 16 KB
  ushort_t* W_lds = (ushort_t*)smem;            // [64 slots][136 tokens] (epilogue)
  ushort_t* V_lds = (ushort_t*)(smem + 17408);  // [64 dims ][136 tokens]

  const int tid  = threadIdx.x;
  const int lane = tid & 63, w = tid >> 6;
  const int wm = w & 1, wn = w >> 1;
  const int m16 = lane & 15, q = lane >> 4;
  const int m7 = m16 & 7;

  const int id = blockIdx.x;
  const int h  = (id >> 3) & 7;
  const int cg = (id & 7) | ((id >> 6) << 3);   // 0..255

  f32x4 acc2[4] = {};
  float csum[4] = {0.f, 0.f, 0.f, 0.f};

  for (int cc = 0; cc < 2; ++cc) {
    const float* Xc = X + (size_t)(cg * 2 + cc) * 128 * D;
    f32x4 acc[4][4] = {};

    for (int kb = 0; kb < D; kb += 64) {
      __syncthreads();
      // stage A: 128 tok x 64 k, fp32 -> bf16 via registers (swizzled ds_write)
      #pragma unroll
      for (int m = 0; m < 4; ++m) {
        int F = tid + m * 256;                  // 0..1023
        int token = F >> 3, c = F & 7;
        const float* src = Xc + (size_t)token * D + kb + c * 8;
        f32x4 a = *(const f32x4*)src;
        f32x4 b2 = *(const f32x4*)(src + 4);
        *(bf16x8*)(A_lds + ((size_t)token * 8 + (c ^ (token & 7))) * 8) = cvt8(a, b2);
      }
      // stage B: 128 cols x 64 k bf16 via global_load_lds (swizzled source chunk)
      #pragma unroll
      for (int m = 0; m < 4; ++m) {
        int li = tid + m * 256;                 // 0..1023
        int col = li >> 3, cs = li & 7;
        int kc = cs ^ (col & 7);
        gload16(Wb2 + (size_t)(h * 128 + col) * D + kb + kc * 8, B_lds + (size_t)li * 8);
      }
      __syncthreads();
      #pragma unroll
      for (int ks = 0; ks < 2; ++ks) {
        bf16x8 af[4], bfv[4];
        #pragma unroll
        for (int i = 0; i < 4; ++i)
          af[i] = *(const bf16x8*)(A_lds + ((size_t)(wm*64 + i*16 + m16) * 8 + ((ks*4 + q) ^ m7)) * 8);
        #pragma unroll
        for (int j = 0; j < 4; ++j)
          bfv[j] = *(const bf16x8*)(B_lds + ((size_t)(wn*64 + j*16 + m16) * 8 + ((ks*4 + q) ^ m7)) * 8);
        #pragma unroll
        for (int i = 0; i < 4; ++i)
          #pragma unroll
          for (int j = 0; j < 4; ++j)
            acc[i][j] = __builtin_amdgcn_mfma_f32_16x16x32_bf16(af[i], bfv[j], acc[i][j], 0, 0, 0);
      }
    }
    __syncthreads();

    // softmax over slots. No max-subtract (|logits| ~ 0.6 std), but clamp at +30
    // so any data bug yields wrong-but-finite output instead of NaN.
    if (wn == 0) {
      float bqv[4];
      #pragma unroll
      for (int j = 0; j < 4; ++j) bqv[j] = bq[h * KS + j * 16 + m16];
      #pragma unroll
      for (int i = 0; i < 4; ++i) {
        us4 wp[4];
        #pragma unroll
        for (int r = 0; r < 4; ++r) {
          float v0 = __expf(fminf(acc[i][0][r] + bqv[0], 30.f));
          float v1 = __expf(fminf(acc[i][1][r] + bqv[1], 30.f));
          float v2 = __expf(fminf(acc[i][2][r] + bqv[2], 30.f));
          float v3 = __expf(fminf(acc[i][3][r] + bqv[3], 30.f));
          float s = v0 + v1 + v2 + v3;
          s += __shfl_xor(s, 1); s += __shfl_xor(s, 2);
          s += __shfl_xor(s, 4); s += __shfl_xor(s, 8);
          float inv = __builtin_amdgcn_rcpf(s);
          v0 *= inv; v1 *= inv; v2 *= inv; v3 *= inv;
          csum[0] += v0; csum[1] += v1; csum[2] += v2; csum[3] += v3;
          wp[0][r] = f2bf(v0); wp[1][r] = f2bf(v1);
          wp[2][r] = f2bf(v2); wp[3][r] = f2bf(v3);
        }
        #pragma unroll
        for (int j = 0; j < 4; ++j)
          *(us4*)(W_lds + (j * 16 + m16) * 136 + wm * 64 + i * 16 + q * 4) = wp[j];
      }
    } else {
      float bvv[4];
      #pragma unroll
      for (int j = 0; j < 4; ++j) bvv[j] = bv[h * HD + j * 16 + m16];
      #pragma unroll
      for (int i = 0; i < 4; ++i)
        #pragma unroll
        for (int j = 0; j < 4; ++j) {
          us4 pk;
          pk.x = f2bf(acc[i][j][0] + bvv[j]);
          pk.y = f2bf(acc[i][j][1] + bvv[j]);
          pk.z = f2bf(acc[i][j][2] + bvv[j]);
          pk.w = f2bf(acc[i][j][3] + bvv[j]);
          *(us4*)(V_lds + (j * 16 + m16) * 136 + wm * 64 + i * 16 + q * 4) = pk;
        }
    }
    __syncthreads();

    // phase 2: S_part[slot][d] += sum_tokens W^T V ; each wave: 16 slots x 64 d
    #pragma unroll
    for (int kk = 0; kk < 4; ++kk) {
      bf16x8 a = *(const bf16x8*)(W_lds + (w * 16 + m16) * 136 + kk * 32 + q * 8);
      #pragma unroll
      for (int j = 0; j < 4; ++j) {
        bf16x8 bb = *(const bf16x8*)(V_lds + (j * 16 + m16) * 136 + kk * 32 + q * 8);
        acc2[j] = __builtin_amdgcn_mfma_f32_16x16x32_bf16(a, bb, acc2[j], 0, 0, 0);
      }
    }
  }

  // flush partials (plain stores — no atomics, no init required)
  const int sidx = cg * 8 + h;
  float* Sb = Spart + (size_t)sidx * (KS * HD);
  #pragma unroll
  for (int j = 0; j < 4; ++j)
    #pragma unroll
    for (int r = 0; r < 4; ++r)
      Sb[(w * 16 + q * 4 + r) * HD + j * 16 + m16] = acc2[j][r];

  // Cpart: wave 0 (wm=0) and wave 1 (wm=1) hold different token halves ->
  // store to DISTINCT slots (r5 bug: both stored to the same address).
  if (wn == 0) {
    #pragma unroll
    for (int j = 0; j < 4; ++j) {
      float c = csum[j];
      c += __shfl_xor(c, 16);
      c += __shfl_xor(c, 32);
      if (q == 0) Cpart[(size_t)sidx * 128 + wm * 64 + j * 16 + m16] = c;
    }
  }
}

// ---------- finalize: reduce 32 chunk-partials, divide by (C+eps), layernorm ----------
__global__ void finalize_kernel(const float* __restrict__ Spart, const float* __restrict__ Cpart,
                                const float* __restrict__ g, const float* __restrict__ bb,
                                float* __restrict__ out) {
  __shared__ float red[8];
  int bk_ = blockIdx.x;                 // b*64 + k
  int b = bk_ >> 6, k = bk_ & 63;
  int tid = threadIdx.x;
  float v[2];
  #pragma unroll
  for (int m = 0; m < 2; ++m) {
    int d = tid + m * 256;
    int h = d >> 6, dd = d & 63;
    float s = 0.f, c = 0.f;
    #pragma unroll 4
    for (int i = 0; i < 32; ++i) {
      int sidx = (b * 32 + i) * 8 + h;
      s += Spart[(size_t)sidx * (KS * HD) + k * HD + dd];
      c += Cpart[(size_t)sidx * 128 + k] + Cpart[(size_t)sidx * 128 + 64 + k];
    }
    v[m] = s / (c + EPS);
  }
  float s1 = v[0] + v[1], s2 = v[0]*v[0] + v[1]*v[1];
  for (int off = 32; off; off >>= 1) { s1 += __shfl_xor(s1, off); s2 += __shfl_xor(s2, off); }
  if ((tid & 63) == 0) { red[tid >> 6] = s1; red[4 + (tid >> 6)] = s2; }
  __syncthreads();
  s1 = red[0] + red[1] + red[2] + red[3];
  s2 = red[4] + red[5] + red[6] + red[7];
  float mu = s1 / D;
  float var = s2 / D - mu * mu;
  float rs = rsqrtf(var + LNEPS);
  #pragma unroll
  for (int m = 0; m < 2; ++m) {
    int d = tid + m * 256;
    out[(size_t)bk_ * D + d] = (v[m] - mu) * rs * g[d] + bb[d];
  }
}

extern "C" void kernel_launch(void* const* d_in, const int* in_sizes, int n_in,
                              void* d_out, int out_size, void* d_ws, size_t ws_size,
                              hipStream_t stream) {
  const float* X       = (const float*)d_in[0];
  const float* slots_w = (const float*)d_in[1];
  const float* g_slots = (const float*)d_in[2];
  const float* b_slots = (const float*)d_in[3];
  const float* Wk      = (const float*)d_in[4];
  const float* bk      = (const float*)d_in[5];
  const float* Wv      = (const float*)d_in[6];
  const float* bv      = (const float*)d_in[7];
  const float* g_after = (const float*)d_in[8];
  const float* b_after = (const float*)d_in[9];
  float* ws    = (float*)d_ws;
  float* bq    = ws + OFF_BQ;
  ushort_t* Wb2 = (ushort_t*)(ws + OFF_WB2);
  float* Spart = ws + OFF_SPART;
  float* Cpart = ws + OFF_CPART;
  float* out   = (float*)d_out;

  hipLaunchKernelGGL(setup_kernel, dim3(512), dim3(256), 0, stream,
                     slots_w, g_slots, b_slots, Wk, bk, Wv, Wb2, bq);
  hipLaunchKernelGGL(main_kernel5, dim3(2048), dim3(256), 0, stream,
                     X, Wb2, bq, bv, Spart, Cpart);
  hipLaunchKernelGGL(finalize_kernel, dim3(B * KS), dim3(256), 0, stream,
                     Spart, Cpart, g_after, b_after, out);
}